// Round 3
// baseline (126.241 us; speedup 1.0000x reference)
//
#include <hip/hip_runtime.h>
#include <hip/hip_cooperative_groups.h>

namespace cg = cooperative_groups;

// privacyLoss1: result = (0.5/N) * sum_{i in [0,N-2], j in [1,N-1]} sign_ij * ||x_i - x_j||^2
// sign_ij = +1 if label_i == label_j else -1.
//
// Factorization: sign = 2*[same] - 1  =>  Total = 2*A - B with
//   A = sum_c [ nC_c*SsqR_c + nR_c*SsqC_c - 2*<VR_c, VC_c> ]
//   B = (N-1)*(SsqR + SsqC) - 2*<VR, VC>
// R = rows except N-1, C = rows except 0. All terms derive from full-set
// per-class stats (n_c, Ssq_c, V_c) + O(D) corrections with x_0, x_{N-1}.
// => O(N*D) streaming instead of O(N^2 D).
//
// v3: single cooperative kernel (phaseA partials -> grid.sync -> phaseB tree
// reduce -> grid.sync -> phaseC fp64 combine). Kills 2 launch gaps and the
// slow single-block reductions of v2.

#define NCLS 10
#define NV3  34   // 10 VV + 10 V0 + 10 VN + VVt,d0N,s0,sN

__global__ __launch_bounds__(256, 4) void fused_kernel(
        const float* __restrict__ x, const int* __restrict__ label,
        float* __restrict__ Vpart, float* __restrict__ Spart,
        float* __restrict__ V, float* __restrict__ scal,
        float* __restrict__ result,
        int N, int D, int S, int G, int rowsPerBlock) {
    cg::grid_group grid = cg::this_grid();
    const int t = threadIdx.x;
    const int b = blockIdx.x;

    __shared__ int   labs[256];
    __shared__ float lsv[4][NCLS][64];
    __shared__ float lss[4][NCLS];
    __shared__ float red[4][NV3];

    // ---------------- phase A: per-(group,slice) partial stats ----------------
    {
        const int s = b % S, g = b / S;
        const int row0 = g * rowsPerBlock;
        const int rows = min(rowsPerBlock, N - row0);
        for (int r = t; r < rows; r += 256) labs[r] = label[row0 + r];
        __syncthreads();

        const int sub = t >> 4;   // 0..15 row phase
        const int l16 = t & 15;   // float4 slot in 64-float slice

        float4 vacc[NCLS];
        float  sacc[NCLS];
#pragma unroll
        for (int c = 0; c < NCLS; ++c) {
            vacc[c] = make_float4(0.f, 0.f, 0.f, 0.f);
            sacc[c] = 0.f;
        }

        const float* bp = x + (size_t)row0 * D + s * 64 + l16 * 4;
#pragma unroll 4
        for (int r = sub; r < rows; r += 16) {
            float4 v = *(const float4*)(bp + (size_t)r * D);
            int l = labs[r];
            float sq = v.x * v.x + v.y * v.y + v.z * v.z + v.w * v.w;
#pragma unroll
            for (int c = 0; c < NCLS; ++c) {
                float m = (l == c) ? 1.0f : 0.0f;
                vacc[c].x = fmaf(m, v.x, vacc[c].x);
                vacc[c].y = fmaf(m, v.y, vacc[c].y);
                vacc[c].z = fmaf(m, v.z, vacc[c].z);
                vacc[c].w = fmaf(m, v.w, vacc[c].w);
                sacc[c]   = fmaf(m, sq, sacc[c]);
            }
        }

        // reduce row-phase bits 4,5 within wave for vacc; whole wave for sacc
#pragma unroll
        for (int c = 0; c < NCLS; ++c) {
            vacc[c].x += __shfl_xor(vacc[c].x, 16, 64);
            vacc[c].y += __shfl_xor(vacc[c].y, 16, 64);
            vacc[c].z += __shfl_xor(vacc[c].z, 16, 64);
            vacc[c].w += __shfl_xor(vacc[c].w, 16, 64);
            vacc[c].x += __shfl_xor(vacc[c].x, 32, 64);
            vacc[c].y += __shfl_xor(vacc[c].y, 32, 64);
            vacc[c].z += __shfl_xor(vacc[c].z, 32, 64);
            vacc[c].w += __shfl_xor(vacc[c].w, 32, 64);
#pragma unroll
            for (int off = 32; off > 0; off >>= 1)
                sacc[c] += __shfl_xor(sacc[c], off, 64);
        }

        const int w = t >> 6;
        if ((t & 63) < 16) {
#pragma unroll
            for (int c = 0; c < NCLS; ++c)
                *(float4*)&lsv[w][c][l16 * 4] = vacc[c];
        }
        if ((t & 63) == 0) {
#pragma unroll
            for (int c = 0; c < NCLS; ++c) lss[w][c] = sacc[c];
        }
        __syncthreads();

        for (int e = t; e < NCLS * 64; e += 256) {
            int c = e >> 6, dd = e & 63;
            float vs = lsv[0][c][dd] + lsv[1][c][dd] + lsv[2][c][dd] + lsv[3][c][dd];
            Vpart[((size_t)g * NCLS + c) * D + s * 64 + dd] = vs;
        }
        if (t < NCLS)
            Spart[(size_t)b * NCLS + t] =
                lss[0][t] + lss[1][t] + lss[2][t] + lss[3][t];
    }

    grid.sync();

    // ---------------- phase B: tree reductions ----------------
    const int nVblocks = (NCLS * D) >> 8;   // 40 for D=1024
    if (b < nVblocks) {
        const int e = (b << 8) + t;         // index into [NCLS*D)
        float acc = 0.f;
        for (int g = 0; g < G; ++g) acc += Vpart[(size_t)g * NCLS * D + e];
        V[e] = acc;
    } else if (b == nVblocks) {
        // per-class label counts
        float cnt[NCLS];
#pragma unroll
        for (int c = 0; c < NCLS; ++c) cnt[c] = 0.f;
        for (int i = t; i < N; i += 256) {
            int l = label[i];
#pragma unroll
            for (int c = 0; c < NCLS; ++c) cnt[c] += (l == c) ? 1.0f : 0.0f;
        }
        const int lane = t & 63, w = t >> 6;
#pragma unroll
        for (int c = 0; c < NCLS; ++c) {
            float v = cnt[c];
#pragma unroll
            for (int off = 32; off > 0; off >>= 1) v += __shfl_xor(v, off, 64);
            if (lane == 0) lss[w][c] = v;
        }
        __syncthreads();
        if (t < NCLS) scal[t] = lss[0][t] + lss[1][t] + lss[2][t] + lss[3][t];
    } else if (b == nVblocks + 1) {
        // Ssq[c] = sum of Spart
        float sp[NCLS];
#pragma unroll
        for (int c = 0; c < NCLS; ++c) sp[c] = 0.f;
        const int nPart = G * S;
        for (int i = t; i < nPart; i += 256) {
#pragma unroll
            for (int c = 0; c < NCLS; ++c) sp[c] += Spart[(size_t)i * NCLS + c];
        }
        const int lane = t & 63, w = t >> 6;
#pragma unroll
        for (int c = 0; c < NCLS; ++c) {
            float v = sp[c];
#pragma unroll
            for (int off = 32; off > 0; off >>= 1) v += __shfl_xor(v, off, 64);
            if (lane == 0) lss[w][c] = v;
        }
        __syncthreads();
        if (t < NCLS) scal[NCLS + t] = lss[0][t] + lss[1][t] + lss[2][t] + lss[3][t];
    }

    grid.sync();

    // ---------------- phase C: closed-form combine (block 0, fp64 tail) ----------------
    if (b == 0) {
        const int lane = t & 63, wave = t >> 6;

        float VV[NCLS], V0[NCLS], VN[NCLS];
#pragma unroll
        for (int c = 0; c < NCLS; ++c) { VV[c] = 0.f; V0[c] = 0.f; VN[c] = 0.f; }
        float VVt = 0.f, d0N = 0.f, s0 = 0.f, sN = 0.f;

        const float* x0 = x;
        const float* xN = x + (size_t)(N - 1) * D;
        for (int d = t; d < D; d += 256) {
            float a0 = x0[d], aN = xN[d];
            float vt = 0.f;
#pragma unroll
            for (int c = 0; c < NCLS; ++c) {
                float v = V[c * D + d];
                VV[c] += v * v;
                V0[c] += v * a0;
                VN[c] += v * aN;
                vt    += v;
            }
            VVt += vt * vt;
            d0N += a0 * aN;
            s0  += a0 * a0;
            sN  += aN * aN;
        }

        float vals[NV3];
#pragma unroll
        for (int c = 0; c < NCLS; ++c) {
            vals[c]      = VV[c];
            vals[10 + c] = V0[c];
            vals[20 + c] = VN[c];
        }
        vals[30] = VVt; vals[31] = d0N; vals[32] = s0; vals[33] = sN;

#pragma unroll
        for (int k = 0; k < NV3; ++k) {
            float v = vals[k];
#pragma unroll
            for (int off = 32; off > 0; off >>= 1) v += __shfl_xor(v, off, 64);
            if (lane == 0) red[wave][k] = v;
        }
        __syncthreads();

        if (t == 0) {
            double v[NV3];
            for (int k = 0; k < NV3; ++k)
                v[k] = (double)red[0][k] + (double)red[1][k] + (double)red[2][k] + (double)red[3][k];

            const int l0 = label[0];
            const int lN = label[N - 1];
            const double sq0 = v[32], sqN = v[33], dON = v[31], VVtd = v[30];

            double A = 0.0, SsqTot = 0.0, Vt0 = 0.0, VtN = 0.0;
            for (int c = 0; c < NCLS; ++c) {
                double nc   = (double)scal[c];
                double Ssqc = (double)scal[NCLS + c];
                SsqTot += Ssqc;
                Vt0    += v[10 + c];
                VtN    += v[20 + c];
                double ac = (lN == c) ? 1.0 : 0.0;  // excluded from rows R
                double bc = (l0 == c) ? 1.0 : 0.0;  // excluded from cols C
                double nR = nc - ac, nC = nc - bc;
                double SsqR  = Ssqc - ac * sqN;
                double SsqC  = Ssqc - bc * sq0;
                double dotRC = v[c] - bc * v[10 + c] - ac * v[20 + c] + ac * bc * dON;
                A += nC * SsqR + nR * SsqC - 2.0 * dotRC;
            }
            double Bv = (double)(N - 1) * ((SsqTot - sqN) + (SsqTot - sq0))
                      - 2.0 * (VVtd - Vt0 - VtN + dON);
            double total = 2.0 * A - Bv;
            result[0] = (float)((0.5 / (double)N) * total);
        }
    }
}

// ======================= fallback path (v2, non-cooperative) =======================
__global__ __launch_bounds__(256) void partial_kernel(
        const float* __restrict__ x, const int* __restrict__ label,
        float* __restrict__ Vpart, float* __restrict__ Spart,
        int N, int D, int S, int rowsPerBlock) {
    const int t = threadIdx.x;
    const int s = blockIdx.x % S;
    const int g = blockIdx.x / S;
    const int row0 = g * rowsPerBlock;
    const int rows = min(rowsPerBlock, N - row0);

    __shared__ int labs[256];
    for (int r = t; r < rows; r += 256) labs[r] = label[row0 + r];
    __syncthreads();

    const int sub = t >> 4;
    const int l16 = t & 15;

    float4 vacc[NCLS];
    float  sacc[NCLS];
#pragma unroll
    for (int c = 0; c < NCLS; ++c) {
        vacc[c] = make_float4(0.f, 0.f, 0.f, 0.f);
        sacc[c] = 0.f;
    }

    const float* bp = x + (size_t)row0 * D + s * 64 + l16 * 4;
#pragma unroll 4
    for (int r = sub; r < rows; r += 16) {
        float4 v = *(const float4*)(bp + (size_t)r * D);
        int l = labs[r];
        float sq = v.x * v.x + v.y * v.y + v.z * v.z + v.w * v.w;
#pragma unroll
        for (int c = 0; c < NCLS; ++c) {
            float m = (l == c) ? 1.0f : 0.0f;
            vacc[c].x = fmaf(m, v.x, vacc[c].x);
            vacc[c].y = fmaf(m, v.y, vacc[c].y);
            vacc[c].z = fmaf(m, v.z, vacc[c].z);
            vacc[c].w = fmaf(m, v.w, vacc[c].w);
            sacc[c]   = fmaf(m, sq, sacc[c]);
        }
    }
#pragma unroll
    for (int c = 0; c < NCLS; ++c) {
        vacc[c].x += __shfl_xor(vacc[c].x, 16, 64);
        vacc[c].y += __shfl_xor(vacc[c].y, 16, 64);
        vacc[c].z += __shfl_xor(vacc[c].z, 16, 64);
        vacc[c].w += __shfl_xor(vacc[c].w, 16, 64);
        vacc[c].x += __shfl_xor(vacc[c].x, 32, 64);
        vacc[c].y += __shfl_xor(vacc[c].y, 32, 64);
        vacc[c].z += __shfl_xor(vacc[c].z, 32, 64);
        vacc[c].w += __shfl_xor(vacc[c].w, 32, 64);
#pragma unroll
        for (int off = 32; off > 0; off >>= 1)
            sacc[c] += __shfl_xor(sacc[c], off, 64);
    }

    const int w = t >> 6;
    __shared__ float lsv[4][NCLS][64];
    __shared__ float lss[4][NCLS];
    if ((t & 63) < 16) {
#pragma unroll
        for (int c = 0; c < NCLS; ++c)
            *(float4*)&lsv[w][c][l16 * 4] = vacc[c];
    }
    if ((t & 63) == 0) {
#pragma unroll
        for (int c = 0; c < NCLS; ++c) lss[w][c] = sacc[c];
    }
    __syncthreads();

    for (int e = t; e < NCLS * 64; e += 256) {
        int c = e >> 6, dd = e & 63;
        float vs = lsv[0][c][dd] + lsv[1][c][dd] + lsv[2][c][dd] + lsv[3][c][dd];
        Vpart[((size_t)g * NCLS + c) * D + s * 64 + dd] = vs;
    }
    if (t < NCLS)
        Spart[(size_t)blockIdx.x * NCLS + t] =
            lss[0][t] + lss[1][t] + lss[2][t] + lss[3][t];
}

__global__ __launch_bounds__(256) void reduceV_kernel(
        const float* __restrict__ Vpart, float* __restrict__ V, int D, int G) {
    const int t = threadIdx.x;
    const int d0 = blockIdx.x * 16;
    for (int e = t; e < NCLS * 16; e += 256) {
        int c = e >> 4, dd = e & 15;
        size_t off = (size_t)c * D + d0 + dd;
        float acc = 0.f;
#pragma unroll 4
        for (int g = 0; g < G; ++g)
            acc += Vpart[(size_t)g * NCLS * D + off];
        V[off] = acc;
    }
}

__global__ __launch_bounds__(256) void finalize_kernel(
        const float* __restrict__ x, const int* __restrict__ label,
        const float* __restrict__ V, const float* __restrict__ Spart, int nSpart,
        float* __restrict__ result, int N, int D) {
    const int t    = threadIdx.x;
    const int lane = t & 63;
    const int wave = t >> 6;

    float cnt[NCLS];
#pragma unroll
    for (int c = 0; c < NCLS; ++c) cnt[c] = 0.0f;
    for (int i = t; i < N; i += 256) {
        int l = label[i];
#pragma unroll
        for (int c = 0; c < NCLS; ++c) cnt[c] += (l == c) ? 1.0f : 0.0f;
    }

    float VV[NCLS], V0[NCLS], VN[NCLS];
#pragma unroll
    for (int c = 0; c < NCLS; ++c) { VV[c] = 0.0f; V0[c] = 0.0f; VN[c] = 0.0f; }
    float VVt = 0.0f, d0N = 0.0f, s0 = 0.0f, sN = 0.0f;

    const float* x0 = x;
    const float* xN = x + (size_t)(N - 1) * D;
    for (int d = t; d < D; d += 256) {
        float a0 = x0[d], aN = xN[d];
        float vt = 0.0f;
#pragma unroll
        for (int c = 0; c < NCLS; ++c) {
            float v = V[c * D + d];
            VV[c] += v * v;
            V0[c] += v * a0;
            VN[c] += v * aN;
            vt    += v;
        }
        VVt += vt * vt;
        d0N += a0 * aN;
        s0  += a0 * a0;
        sN  += aN * aN;
    }

    float ssqp[NCLS];
#pragma unroll
    for (int c = 0; c < NCLS; ++c) ssqp[c] = 0.0f;
    for (int bb = t; bb < nSpart; bb += 256) {
#pragma unroll
        for (int c = 0; c < NCLS; ++c) ssqp[c] += Spart[(size_t)bb * NCLS + c];
    }

    const int NVALS = 54;
    float vals[54];
#pragma unroll
    for (int c = 0; c < NCLS; ++c) {
        vals[c]      = VV[c];
        vals[10 + c] = V0[c];
        vals[20 + c] = VN[c];
        vals[34 + c] = cnt[c];
        vals[44 + c] = ssqp[c];
    }
    vals[30] = VVt; vals[31] = d0N; vals[32] = s0; vals[33] = sN;

    __shared__ float red[4][54];
#pragma unroll
    for (int k = 0; k < NVALS; ++k) {
        float v = vals[k];
#pragma unroll
        for (int off = 32; off > 0; off >>= 1) v += __shfl_xor(v, off, 64);
        if (lane == 0) red[wave][k] = v;
    }
    __syncthreads();

    if (t == 0) {
        double v[54];
        for (int k = 0; k < NVALS; ++k)
            v[k] = (double)red[0][k] + (double)red[1][k] + (double)red[2][k] + (double)red[3][k];

        const int l0 = label[0];
        const int lN = label[N - 1];
        const double sq0 = v[32], sqN = v[33], dON = v[31], VVtd = v[30];

        double A = 0.0, SsqTot = 0.0, Vt0 = 0.0, VtN = 0.0;
        for (int c = 0; c < NCLS; ++c) {
            double nc   = v[34 + c];
            double Ssqc = v[44 + c];
            SsqTot += Ssqc;
            Vt0    += v[10 + c];
            VtN    += v[20 + c];
            double ac = (lN == c) ? 1.0 : 0.0;
            double bc = (l0 == c) ? 1.0 : 0.0;
            double nR = nc - ac, nC = nc - bc;
            double SsqR  = Ssqc - ac * sqN;
            double SsqC  = Ssqc - bc * sq0;
            double dotRC = v[c] - bc * v[10 + c] - ac * v[20 + c] + ac * bc * dON;
            A += nC * SsqR + nR * SsqC - 2.0 * dotRC;
        }
        double Bv = (double)(N - 1) * ((SsqTot - sqN) + (SsqTot - sq0))
                  - 2.0 * (VVtd - Vt0 - VtN + dON);
        double total = 2.0 * A - Bv;
        result[0] = (float)((0.5 / (double)N) * total);
    }
}

extern "C" void kernel_launch(void* const* d_in, const int* in_sizes, int n_in,
                              void* d_out, int out_size, void* d_ws, size_t ws_size,
                              hipStream_t stream) {
    const float* x     = (const float*)d_in[0];
    const int*   label = (const int*)d_in[1];
    const int N = in_sizes[1];
    const int D = in_sizes[0] / N;   // 1024
    float* result = (float*)d_out;

    const size_t wsFloats = ws_size / sizeof(float);

    // ---- try cooperative fused path ----
    int rpb = 128;
    bool coop = (D % 64 == 0) && ((NCLS * D) % 256 == 0) && (N % rpb == 0);
    int S = 0, G = 0, gridSz = 0;
    if (coop) {
        S = D / 64;
        G = N / rpb;
        gridSz = G * S;
        const int nVblocks = (NCLS * D) >> 8;
        coop = gridSz >= nVblocks + 2;
        size_t need = (size_t)G * NCLS * D + (size_t)gridSz * NCLS
                    + (size_t)NCLS * D + 32;
        coop = coop && (need <= wsFloats);
    }
    if (coop) {
        int dev = 0;
        hipGetDevice(&dev);
        int numCU = 0;
        hipDeviceGetAttribute(&numCU, hipDeviceAttributeMultiprocessorCount, dev);
        int maxB = 0;
        hipOccupancyMaxActiveBlocksPerMultiprocessor(&maxB, fused_kernel, 256, 0);
        if ((long)maxB * (long)numCU < (long)gridSz) coop = false;
    }

    if (coop) {
        float* Vpart = (float*)d_ws;                           // [G][NCLS][D]
        float* Spart = Vpart + (size_t)G * NCLS * D;           // [grid][NCLS]
        float* V     = Spart + (size_t)gridSz * NCLS;          // [NCLS][D]
        float* scal  = V + (size_t)NCLS * D;                   // [2*NCLS]
        int n = N, d = D, s = S, g = G, r = rpb;
        void* args[] = { (void*)&x, (void*)&label, (void*)&Vpart, (void*)&Spart,
                         (void*)&V, (void*)&scal, (void*)&result,
                         (void*)&n, (void*)&d, (void*)&s, (void*)&g, (void*)&r };
        hipLaunchCooperativeKernel((const void*)fused_kernel, dim3(gridSz), dim3(256),
                                   args, 0, stream);
        return;
    }

    // ---- fallback: 3-kernel tree (v2) ----
    const int S2 = D / 64;
    int rpb2 = 0, Ga = 0;
    const int cands[3] = {64, 128, 256};
    for (int i = 0; i < 3; ++i) {
        int Gc = (N + cands[i] - 1) / cands[i];
        size_t need = (size_t)Gc * NCLS * D + (size_t)Gc * S2 * NCLS + (size_t)NCLS * D;
        if (need <= wsFloats) { rpb2 = cands[i]; Ga = Gc; break; }
    }
    float* Vpart = (float*)d_ws;
    float* Spart = Vpart + (size_t)Ga * NCLS * D;
    float* V     = Spart + (size_t)Ga * S2 * NCLS;
    partial_kernel<<<Ga * S2, 256, 0, stream>>>(x, label, Vpart, Spart, N, D, S2, rpb2);
    reduceV_kernel<<<D / 16, 256, 0, stream>>>(Vpart, V, D, Ga);
    finalize_kernel<<<1, 256, 0, stream>>>(x, label, V, Spart, Ga * S2, result, N, D);
}

// Round 4
// 34.957 us; speedup vs baseline: 3.6113x; 3.6113x over previous
//
#include <hip/hip_runtime.h>

// privacyLoss1: result = (0.5/N) * sum_{i in [0,N-2], j in [1,N-1]} sign_ij * ||x_i - x_j||^2
// sign_ij = +1 if label_i == label_j else -1.
//
// Factorization: sign = 2*[same] - 1  =>  Total = 2*A - B with
//   A = sum_c [ nC_c*SsqR_c + nR_c*SsqC_c - 2*<VR_c, VC_c> ]
//   B = (N-1)*(SsqR + SsqC) - 2*<VR, VC>
// R = rows except N-1, C = rows except 0. All terms derive from full-set
// per-class stats (n_c, Ssq_c, V_c) + O(D) corrections with x_0, x_{N-1}.
// => O(N*D) streaming instead of O(N^2 D).
//
// v4: two dispatches. Phase A: (row-group x dim-slice) float4 partials ->
// disjoint ws slabs (no atomics, no zeroing); also resets the done-counter.
// Finish kernel: 42 blocks (40 reduce Vpart->V, 1 label counts, 1 Spart
// reduce); LAST block (device-scope atomic counter + threadfence, rocPRIM
// pattern -- NOT a CG grid barrier, which measured ~50us/sync on 8 XCDs in
// v3) runs the fp64 closed-form combine on the L2-hot V.

#define NCLS 10
#define NV3  34   // 10 VV + 10 V0 + 10 VN + VVt,d0N,s0,sN

// ---------------- dispatch 1: per-(group,slice) partial stats ----------------
__global__ __launch_bounds__(256) void phaseA_kernel(
        const float* __restrict__ x, const int* __restrict__ label,
        float* __restrict__ Vpart, float* __restrict__ Spart,
        unsigned int* __restrict__ done,
        int N, int D, int S, int rowsPerBlock) {
    const int t = threadIdx.x;
    const int b = blockIdx.x;
    if (b == 0 && t == 0) *done = 0u;   // reset for the finish kernel (every call)

    const int s = b % S;                // 64-float dim slice
    const int g = b / S;                // row group
    const int row0 = g * rowsPerBlock;
    const int rows = min(rowsPerBlock, N - row0);

    __shared__ int labs[512];
    for (int r = t; r < rows; r += 256) labs[r] = label[row0 + r];
    __syncthreads();

    const int sub = t >> 4;   // 0..15 row phase
    const int l16 = t & 15;   // float4 slot in 64-float slice

    float4 vacc[NCLS];
    float  sacc[NCLS];
#pragma unroll
    for (int c = 0; c < NCLS; ++c) {
        vacc[c] = make_float4(0.f, 0.f, 0.f, 0.f);
        sacc[c] = 0.f;
    }

    const float* bp = x + (size_t)row0 * D + s * 64 + l16 * 4;
#pragma unroll 4
    for (int r = sub; r < rows; r += 16) {
        float4 v = *(const float4*)(bp + (size_t)r * D);
        int l = labs[r];
        float sq = v.x * v.x + v.y * v.y + v.z * v.z + v.w * v.w;
#pragma unroll
        for (int c = 0; c < NCLS; ++c) {
            float m = (l == c) ? 1.0f : 0.0f;
            vacc[c].x = fmaf(m, v.x, vacc[c].x);
            vacc[c].y = fmaf(m, v.y, vacc[c].y);
            vacc[c].z = fmaf(m, v.z, vacc[c].z);
            vacc[c].w = fmaf(m, v.w, vacc[c].w);
            sacc[c]   = fmaf(m, sq, sacc[c]);
        }
    }

    // reduce row-phase lane bits 4,5 for vacc; whole wave for sacc
#pragma unroll
    for (int c = 0; c < NCLS; ++c) {
        vacc[c].x += __shfl_xor(vacc[c].x, 16, 64);
        vacc[c].y += __shfl_xor(vacc[c].y, 16, 64);
        vacc[c].z += __shfl_xor(vacc[c].z, 16, 64);
        vacc[c].w += __shfl_xor(vacc[c].w, 16, 64);
        vacc[c].x += __shfl_xor(vacc[c].x, 32, 64);
        vacc[c].y += __shfl_xor(vacc[c].y, 32, 64);
        vacc[c].z += __shfl_xor(vacc[c].z, 32, 64);
        vacc[c].w += __shfl_xor(vacc[c].w, 32, 64);
#pragma unroll
        for (int off = 32; off > 0; off >>= 1)
            sacc[c] += __shfl_xor(sacc[c], off, 64);
    }

    const int w = t >> 6;
    __shared__ float lsv[4][NCLS][64];
    __shared__ float lss[4][NCLS];
    if ((t & 63) < 16) {
#pragma unroll
        for (int c = 0; c < NCLS; ++c)
            *(float4*)&lsv[w][c][l16 * 4] = vacc[c];
    }
    if ((t & 63) == 0) {
#pragma unroll
        for (int c = 0; c < NCLS; ++c) lss[w][c] = sacc[c];
    }
    __syncthreads();

    for (int e = t; e < NCLS * 64; e += 256) {
        int c = e >> 6, dd = e & 63;
        float vs = lsv[0][c][dd] + lsv[1][c][dd] + lsv[2][c][dd] + lsv[3][c][dd];
        Vpart[((size_t)g * NCLS + c) * D + s * 64 + dd] = vs;
    }
    if (t < NCLS)
        Spart[(size_t)b * NCLS + t] =
            lss[0][t] + lss[1][t] + lss[2][t] + lss[3][t];
}

// -------- dispatch 2: tree reductions + last-block fp64 combine --------
__global__ __launch_bounds__(256) void finish_kernel(
        const float* __restrict__ x, const int* __restrict__ label,
        const float* __restrict__ Vpart, const float* __restrict__ Spart, int nSpart,
        float* __restrict__ V, float* __restrict__ scal,
        unsigned int* __restrict__ done, float* __restrict__ result,
        int N, int D, int G, int nVblocks) {
    const int t = threadIdx.x;
    const int b = blockIdx.x;
    const int lane = t & 63, w = t >> 6;

    __shared__ float lss[4][NCLS];
    __shared__ float red[4][NV3];

    if (b < nVblocks) {
        const int e = (b << 8) + t;     // index into [NCLS*D)
        float acc = 0.f;
        for (int g = 0; g < G; ++g) acc += Vpart[(size_t)g * NCLS * D + e];
        V[e] = acc;
    } else if (b == nVblocks) {
        // per-class label counts (exact in fp32: counts <= N)
        float cnt[NCLS];
#pragma unroll
        for (int c = 0; c < NCLS; ++c) cnt[c] = 0.f;
        for (int i = t; i < N; i += 256) {
            int l = label[i];
#pragma unroll
            for (int c = 0; c < NCLS; ++c) cnt[c] += (l == c) ? 1.0f : 0.0f;
        }
#pragma unroll
        for (int c = 0; c < NCLS; ++c) {
            float v = cnt[c];
#pragma unroll
            for (int off = 32; off > 0; off >>= 1) v += __shfl_xor(v, off, 64);
            if (lane == 0) lss[w][c] = v;
        }
        __syncthreads();
        if (t < NCLS) scal[t] = lss[0][t] + lss[1][t] + lss[2][t] + lss[3][t];
    } else {
        // Ssq[c] = sum over Spart
        float sp[NCLS];
#pragma unroll
        for (int c = 0; c < NCLS; ++c) sp[c] = 0.f;
        for (int i = t; i < nSpart; i += 256) {
#pragma unroll
            for (int c = 0; c < NCLS; ++c) sp[c] += Spart[(size_t)i * NCLS + c];
        }
#pragma unroll
        for (int c = 0; c < NCLS; ++c) {
            float v = sp[c];
#pragma unroll
            for (int off = 32; off > 0; off >>= 1) v += __shfl_xor(v, off, 64);
            if (lane == 0) lss[w][c] = v;
        }
        __syncthreads();
        if (t < NCLS) scal[NCLS + t] = lss[0][t] + lss[1][t] + lss[2][t] + lss[3][t];
    }

    // release our writes, then count this block done
    __threadfence();
    __shared__ int isLast;
    if (t == 0) isLast = (atomicAdd(done, 1u) == (unsigned)(gridDim.x - 1)) ? 1 : 0;
    __syncthreads();
    if (!isLast) return;
    __threadfence();   // acquire side: observe all other blocks' V/scal writes

    // ---------------- phase C: closed-form combine (fp64 tail) ----------------
    float VV[NCLS], V0[NCLS], VN[NCLS];
#pragma unroll
    for (int c = 0; c < NCLS; ++c) { VV[c] = 0.f; V0[c] = 0.f; VN[c] = 0.f; }
    float VVt = 0.f, d0N = 0.f, s0 = 0.f, sN = 0.f;

    const float* x0 = x;
    const float* xN = x + (size_t)(N - 1) * D;
    for (int d = t; d < D; d += 256) {
        float a0 = x0[d], aN = xN[d];
        float vt = 0.f;
#pragma unroll
        for (int c = 0; c < NCLS; ++c) {
            float v = V[c * D + d];
            VV[c] += v * v;
            V0[c] += v * a0;
            VN[c] += v * aN;
            vt    += v;
        }
        VVt += vt * vt;
        d0N += a0 * aN;
        s0  += a0 * a0;
        sN  += aN * aN;
    }

    float vals[NV3];
#pragma unroll
    for (int c = 0; c < NCLS; ++c) {
        vals[c]      = VV[c];
        vals[10 + c] = V0[c];
        vals[20 + c] = VN[c];
    }
    vals[30] = VVt; vals[31] = d0N; vals[32] = s0; vals[33] = sN;

#pragma unroll
    for (int k = 0; k < NV3; ++k) {
        float v = vals[k];
#pragma unroll
        for (int off = 32; off > 0; off >>= 1) v += __shfl_xor(v, off, 64);
        if (lane == 0) red[w][k] = v;
    }
    __syncthreads();

    if (t == 0) {
        double v[NV3];
        for (int k = 0; k < NV3; ++k)
            v[k] = (double)red[0][k] + (double)red[1][k] + (double)red[2][k] + (double)red[3][k];

        const int l0 = label[0];
        const int lN = label[N - 1];
        const double sq0 = v[32], sqN = v[33], dON = v[31], VVtd = v[30];

        double A = 0.0, SsqTot = 0.0, Vt0 = 0.0, VtN = 0.0;
        for (int c = 0; c < NCLS; ++c) {
            double nc   = (double)scal[c];
            double Ssqc = (double)scal[NCLS + c];
            SsqTot += Ssqc;
            Vt0    += v[10 + c];
            VtN    += v[20 + c];
            double ac = (lN == c) ? 1.0 : 0.0;  // excluded from rows R
            double bc = (l0 == c) ? 1.0 : 0.0;  // excluded from cols C
            double nR = nc - ac, nC = nc - bc;
            double SsqR  = Ssqc - ac * sqN;
            double SsqC  = Ssqc - bc * sq0;
            double dotRC = v[c] - bc * v[10 + c] - ac * v[20 + c] + ac * bc * dON;
            A += nC * SsqR + nR * SsqC - 2.0 * dotRC;
        }
        double Bv = (double)(N - 1) * ((SsqTot - sqN) + (SsqTot - sq0))
                  - 2.0 * (VVtd - Vt0 - VtN + dON);
        double total = 2.0 * A - Bv;
        result[0] = (float)((0.5 / (double)N) * total);
    }
}

// ------------------ fallback: v1 atomic path (tiny ws) ------------------
__global__ __launch_bounds__(256) void zero_ws_kernel(float* __restrict__ p, int n) {
    int i = blockIdx.x * 256 + threadIdx.x;
    if (i < n) p[i] = 0.0f;
}

__global__ __launch_bounds__(256) void accum_kernel(
        const float* __restrict__ x, const int* __restrict__ label,
        float* __restrict__ V, float* __restrict__ Ssq,
        int N, int D, int dimSlices, int rowsPerChunk) {
    const int t  = threadIdx.x;
    const int ds = blockIdx.x % dimSlices;
    const int rc = blockIdx.x / dimSlices;
    const int row0 = rc * rowsPerChunk;

    __shared__ int labs[64];
    if (t < rowsPerChunk && row0 + t < N) labs[t] = label[row0 + t];
    __syncthreads();

    const int d = ds * 256 + t;
    float vacc[NCLS], sacc[NCLS];
#pragma unroll
    for (int c = 0; c < NCLS; ++c) { vacc[c] = 0.0f; sacc[c] = 0.0f; }

    const float* p = x + (size_t)row0 * D + d;
    const int rows = (row0 + rowsPerChunk <= N) ? rowsPerChunk : (N - row0);
    for (int r = 0; r < rows; ++r) {
        float v = p[(size_t)r * D];
        int   l = labs[r];
        float sq = v * v;
#pragma unroll
        for (int c = 0; c < NCLS; ++c) {
            float m = (l == c) ? 1.0f : 0.0f;
            vacc[c] = fmaf(m, v, vacc[c]);
            sacc[c] = fmaf(m, sq, sacc[c]);
        }
    }
#pragma unroll
    for (int c = 0; c < NCLS; ++c) atomicAdd(&V[c * D + d], vacc[c]);
    const int lane = t & 63;
#pragma unroll
    for (int c = 0; c < NCLS; ++c) {
        float v = sacc[c];
#pragma unroll
        for (int off = 32; off > 0; off >>= 1) v += __shfl_xor(v, off, 64);
        if (lane == 0) atomicAdd(&Ssq[c], v);
    }
}

__global__ __launch_bounds__(256) void finalize_small_kernel(
        const float* __restrict__ x, const int* __restrict__ label,
        const float* __restrict__ V, const float* __restrict__ Ssq,
        float* __restrict__ result, int N, int D) {
    const int t    = threadIdx.x;
    const int lane = t & 63;
    const int wave = t >> 6;

    float cnt[NCLS];
#pragma unroll
    for (int c = 0; c < NCLS; ++c) cnt[c] = 0.0f;
    for (int i = t; i < N; i += 256) {
        int l = label[i];
#pragma unroll
        for (int c = 0; c < NCLS; ++c) cnt[c] += (l == c) ? 1.0f : 0.0f;
    }

    float VV[NCLS], V0[NCLS], VN[NCLS];
#pragma unroll
    for (int c = 0; c < NCLS; ++c) { VV[c] = 0.0f; V0[c] = 0.0f; VN[c] = 0.0f; }
    float VVt = 0.0f, d0N = 0.0f, s0 = 0.0f, sN = 0.0f;

    const float* x0 = x;
    const float* xN = x + (size_t)(N - 1) * D;
    for (int d = t; d < D; d += 256) {
        float a0 = x0[d], aN = xN[d];
        float vt = 0.0f;
#pragma unroll
        for (int c = 0; c < NCLS; ++c) {
            float v = V[c * D + d];
            VV[c] += v * v;
            V0[c] += v * a0;
            VN[c] += v * aN;
            vt    += v;
        }
        VVt += vt * vt;
        d0N += a0 * aN;
        s0  += a0 * a0;
        sN  += aN * aN;
    }

    float vals[NV3];
#pragma unroll
    for (int c = 0; c < NCLS; ++c) {
        vals[c]      = VV[c];
        vals[10 + c] = V0[c];
        vals[20 + c] = VN[c];
    }
    vals[30] = VVt; vals[31] = d0N; vals[32] = s0; vals[33] = sN;

    __shared__ float red[4][NV3];
#pragma unroll
    for (int k = 0; k < NV3; ++k) {
        float v = vals[k];
#pragma unroll
        for (int off = 32; off > 0; off >>= 1) v += __shfl_xor(v, off, 64);
        if (lane == 0) red[wave][k] = v;
    }
    __syncthreads();

    if (t == 0) {
        double v[NV3];
        for (int k = 0; k < NV3; ++k)
            v[k] = (double)red[0][k] + (double)red[1][k] + (double)red[2][k] + (double)red[3][k];

        float cnt2[NCLS];
#pragma unroll
        for (int c = 0; c < NCLS; ++c) cnt2[c] = 0.f;
        for (int i = 0; i < N; ++i) {
            int l = label[i];
#pragma unroll
            for (int c = 0; c < NCLS; ++c) cnt2[c] += (l == c) ? 1.0f : 0.0f;
        }

        const int l0 = label[0];
        const int lN = label[N - 1];
        const double sq0 = v[32], sqN = v[33], dON = v[31], VVtd = v[30];

        double A = 0.0, SsqTot = 0.0, Vt0 = 0.0, VtN = 0.0;
        for (int c = 0; c < NCLS; ++c) {
            double nc   = (double)cnt2[c];
            double Ssqc = (double)Ssq[c];
            SsqTot += Ssqc;
            Vt0    += v[10 + c];
            VtN    += v[20 + c];
            double ac = (lN == c) ? 1.0 : 0.0;
            double bc = (l0 == c) ? 1.0 : 0.0;
            double nR = nc - ac, nC = nc - bc;
            double SsqR  = Ssqc - ac * sqN;
            double SsqC  = Ssqc - bc * sq0;
            double dotRC = v[c] - bc * v[10 + c] - ac * v[20 + c] + ac * bc * dON;
            A += nC * SsqR + nR * SsqC - 2.0 * dotRC;
        }
        double Bv = (double)(N - 1) * ((SsqTot - sqN) + (SsqTot - sq0))
                  - 2.0 * (VVtd - Vt0 - VtN + dON);
        double total = 2.0 * A - Bv;
        result[0] = (float)((0.5 / (double)N) * total);
    }
}

extern "C" void kernel_launch(void* const* d_in, const int* in_sizes, int n_in,
                              void* d_out, int out_size, void* d_ws, size_t ws_size,
                              hipStream_t stream) {
    const float* x     = (const float*)d_in[0];
    const int*   label = (const int*)d_in[1];
    const int N = in_sizes[1];
    const int D = in_sizes[0] / N;   // 1024
    float* result = (float*)d_out;

    const size_t wsFloats = ws_size / sizeof(float);

    // ---- main path: 2 dispatches, last-block finalize ----
    bool ok = (D % 64 == 0) && ((NCLS * D) % 256 == 0);
    int rpb = 128;
    int S = 0, G = 0, gridA = 0, nVblocks = 0;
    size_t need = 0;
    if (ok) {
        S = D / 64;
        G = (N + rpb - 1) / rpb;
        gridA = G * S;
        nVblocks = (NCLS * D) >> 8;   // 40 for D=1024
        need = (size_t)G * NCLS * D        // Vpart
             + (size_t)gridA * NCLS       // Spart
             + (size_t)NCLS * D           // V
             + 2 * NCLS                   // scal
             + 4;                         // done counter (+pad)
        ok = need <= wsFloats;
    }

    if (ok) {
        float* Vpart = (float*)d_ws;
        float* Spart = Vpart + (size_t)G * NCLS * D;
        float* V     = Spart + (size_t)gridA * NCLS;
        float* scal  = V + (size_t)NCLS * D;
        unsigned int* done = (unsigned int*)(scal + 2 * NCLS);

        phaseA_kernel<<<gridA, 256, 0, stream>>>(
            x, label, Vpart, Spart, done, N, D, S, rpb);
        finish_kernel<<<nVblocks + 2, 256, 0, stream>>>(
            x, label, Vpart, Spart, gridA, V, scal, done, result,
            N, D, G, nVblocks);
        return;
    }

    // ---- fallback: v1 atomic path (needs ~41 KB ws) ----
    float* V   = (float*)d_ws;
    float* Ssq = V + NCLS * D;
    const int nz = NCLS * D + NCLS;
    zero_ws_kernel<<<(nz + 255) / 256, 256, 0, stream>>>(V, nz);
    const int rowsPerChunk = 64;
    const int dimSlices = (D + 255) / 256;
    const int rowChunks = (N + rowsPerChunk - 1) / rowsPerChunk;
    accum_kernel<<<rowChunks * dimSlices, 256, 0, stream>>>(
        x, label, V, Ssq, N, D, dimSlices, rowsPerChunk);
    finalize_small_kernel<<<1, 256, 0, stream>>>(x, label, V, Ssq, result, N, D);
}